// Round 4
// baseline (791.979 us; speedup 1.0000x reference)
//
#include <hip/hip_runtime.h>
#include <hip/hip_fp16.h>
#include <math.h>

typedef float f32x4 __attribute__((ext_vector_type(4)));

#define NPTS 4096
#define DIM  512
#define BK   32
#define LDP  68   // padded LDS row length (floats)

// ws layout (doubles):
#define WS_U_A   0
#define WS_U_B   4096
#define WS_S     8192
#define WS_DOTS  8194
#define WS_SQA   8197
#define WS_SQB   12293
#define WS_ZERO_DOUBLES 8197   // zero everything up to sqa

// ---------------- sq kernel: sq[i] = sum_k x[i][k]^2 (double) -------------
__global__ __launch_bounds__(256) void sq_kernel(const float* __restrict__ fa,
                                                 const float* __restrict__ fb,
                                                 double* __restrict__ ws) {
  int wave = threadIdx.x >> 6, lane = threadIdx.x & 63;
  int row = blockIdx.x * 4 + wave;
  const float* src = blockIdx.y ? fb : fa;
  double*      dst = blockIdx.y ? (ws + WS_SQB) : (ws + WS_SQA);
  const f32x4* p = (const f32x4*)(src + (size_t)row * DIM);
  double s = 0.0;
#pragma unroll
  for (int c = 0; c < DIM / 4 / 64; ++c) {
    f32x4 v = p[lane + c * 64];
    s += (double)v[0]*v[0] + (double)v[1]*v[1] + (double)v[2]*v[2] + (double)v[3]*v[3];
  }
  for (int off = 32; off; off >>= 1) s += __shfl_down(s, off);
  if (lane == 0) dst[row] = s;
}

// distance quantized to IEEE fp16 (hypothesis: reference pipeline stores the
// distance matrix in fp16; everything else exact)
__device__ __forceinline__ double dist_q(double d2) {
  if (d2 <= 0.0) return 0.0;
  float d = (float)sqrt(d2);
  return (double)__half2float(__float2half(d));   // RNE
}

// ---------------- tile kernel, two modes ----------------
// MODE 0: accumulate u (row sums of distance matrices) via f64 atomics.
// MODE 1: literal U-centering: acc Σ (da-ra_i-ra_j+ta)(db-rb_i-rb_j+tb) etc.
template<int MODE>
__global__ __launch_bounds__(256) void tile_kernel(
    const float* __restrict__ fa, const float* __restrict__ fb,
    double* __restrict__ ws)
{
  const int bi = blockIdx.y, bj = blockIdx.x;
  if (bj < bi) return;

  __shared__ float sAI[BK][LDP], sAJ[BK][LDP], sBI[BK][LDP], sBJ[BK][LDP];
  __shared__ double redbuf[16][64];
  __shared__ double wred[4][3];

  const int t  = threadIdx.x;
  const int tx = t & 15, ty = t >> 4;
  const int i0 = bi * 64, j0 = bj * 64;
  const bool diag = (bi == bj);

  double accAd[4][4] = {{0.0}}, accBd[4][4] = {{0.0}};

  for (int k0 = 0; k0 < DIM; k0 += BK) {
    __syncthreads();
#pragma unroll
    for (int h = 0; h < 2; ++h) {
      int rr = (t >> 3) + h * 32;
      int cc = (t & 7) * 4;
      f32x4 va_i = *(const f32x4*)(fa + (size_t)(i0 + rr) * DIM + k0 + cc);
      f32x4 va_j = *(const f32x4*)(fa + (size_t)(j0 + rr) * DIM + k0 + cc);
      f32x4 vb_i = *(const f32x4*)(fb + (size_t)(i0 + rr) * DIM + k0 + cc);
      f32x4 vb_j = *(const f32x4*)(fb + (size_t)(j0 + rr) * DIM + k0 + cc);
#pragma unroll
      for (int u = 0; u < 4; ++u) {
        sAI[cc + u][rr] = va_i[u];
        sAJ[cc + u][rr] = va_j[u];
        sBI[cc + u][rr] = vb_i[u];
        sBJ[cc + u][rr] = vb_j[u];
      }
    }
    __syncthreads();

    float accA[4][4] = {{0.f}}, accB[4][4] = {{0.f}};
#pragma unroll 4
    for (int kk = 0; kk < BK; ++kk) {
      f32x4 aI = *(const f32x4*)&sAI[kk][ty * 4];
      f32x4 aJ = *(const f32x4*)&sAJ[kk][tx * 4];
      f32x4 bI = *(const f32x4*)&sBI[kk][ty * 4];
      f32x4 bJ = *(const f32x4*)&sBJ[kk][tx * 4];
#pragma unroll
      for (int m = 0; m < 4; ++m)
#pragma unroll
        for (int l = 0; l < 4; ++l) {
          accA[m][l] = fmaf(aI[m], aJ[l], accA[m][l]);
          accB[m][l] = fmaf(bI[m], bJ[l], accB[m][l]);
        }
    }
#pragma unroll
    for (int m = 0; m < 4; ++m)
#pragma unroll
      for (int l = 0; l < 4; ++l) {
        accAd[m][l] += (double)accA[m][l];
        accBd[m][l] += (double)accB[m][l];
      }
  }

  // distances for this thread's 4x4 patch (fp16-quantized)
  const double* sqa = ws + WS_SQA;
  const double* sqb = ws + WS_SQB;
  double sia[4], sja[4], sib[4], sjb[4];
#pragma unroll
  for (int m = 0; m < 4; ++m) {
    sia[m] = sqa[i0 + ty * 4 + m];
    sib[m] = sqb[i0 + ty * 4 + m];
    sja[m] = sqa[j0 + tx * 4 + m];
    sjb[m] = sqb[j0 + tx * 4 + m];
  }
  double da[4][4], db[4][4];
#pragma unroll
  for (int m = 0; m < 4; ++m)
#pragma unroll
    for (int l = 0; l < 4; ++l) {
      da[m][l] = dist_q(sia[m] + sja[l] - 2.0 * accAd[m][l]);
      db[m][l] = dist_q(sib[m] + sjb[l] - 2.0 * accBd[m][l]);
      if (diag && (ty * 4 + m == tx * 4 + l)) { da[m][l] = 0.0; db[m][l] = 0.0; }
    }

  if constexpr (MODE == 0) {
    double rsA[4] = {0,0,0,0}, csA[4] = {0,0,0,0};
    double rsB[4] = {0,0,0,0}, csB[4] = {0,0,0,0};
#pragma unroll
    for (int m = 0; m < 4; ++m)
#pragma unroll
      for (int l = 0; l < 4; ++l) {
        rsA[m] += da[m][l]; csA[l] += da[m][l];
        rsB[m] += db[m][l]; csB[l] += db[m][l];
      }
    double* uA = ws + WS_U_A;
    double* uB = ws + WS_U_B;
    __syncthreads();
#pragma unroll
    for (int m = 0; m < 4; ++m) redbuf[tx][ty * 4 + m] = rsA[m];
    __syncthreads();
    if (t < 64) { double s = 0; for (int x = 0; x < 16; ++x) s += redbuf[x][t]; atomicAdd(&uA[i0 + t], s); }
    __syncthreads();
#pragma unroll
    for (int m = 0; m < 4; ++m) redbuf[tx][ty * 4 + m] = rsB[m];
    __syncthreads();
    if (t < 64) { double s = 0; for (int x = 0; x < 16; ++x) s += redbuf[x][t]; atomicAdd(&uB[i0 + t], s); }
    __syncthreads();
    if (!diag) {
#pragma unroll
      for (int l = 0; l < 4; ++l) redbuf[ty][tx * 4 + l] = csA[l];
      __syncthreads();
      if (t < 64) { double s = 0; for (int x = 0; x < 16; ++x) s += redbuf[x][t]; atomicAdd(&uA[j0 + t], s); }
      __syncthreads();
#pragma unroll
      for (int l = 0; l < 4; ++l) redbuf[ty][tx * 4 + l] = csB[l];
      __syncthreads();
      if (t < 64) { double s = 0; for (int x = 0; x < 16; ++x) s += redbuf[x][t]; atomicAdd(&uB[j0 + t], s); }
    }
  } else {
    const double n = (double)NPTS;
    const double inv_nm2 = 1.0 / (n - 2.0);
    const double* uA = ws + WS_U_A;
    const double* uB = ws + WS_U_B;
    const double SA = ws[WS_S + 0], SB = ws[WS_S + 1];
    const double ta = SA / ((n - 1.0) * (n - 2.0));
    const double tb = SB / ((n - 1.0) * (n - 2.0));
    double rai[4], rbi[4], raj[4], rbj[4];
#pragma unroll
    for (int m = 0; m < 4; ++m) {
      rai[m] = uA[i0 + ty * 4 + m] * inv_nm2;
      rbi[m] = uB[i0 + ty * 4 + m] * inv_nm2;
      raj[m] = uA[j0 + tx * 4 + m] * inv_nm2;
      rbj[m] = uB[j0 + tx * 4 + m] * inv_nm2;
    }
    double dab = 0, daa = 0, dbb = 0;
#pragma unroll
    for (int m = 0; m < 4; ++m)
#pragma unroll
      for (int l = 0; l < 4; ++l) {
        double Ac = da[m][l] - rai[m] - raj[l] + ta;
        double Bc = db[m][l] - rbi[m] - rbj[l] + tb;
        if (diag && (ty * 4 + m == tx * 4 + l)) { Ac = 0.0; Bc = 0.0; }
        dab += Ac * Bc;
        daa += Ac * Ac;
        dbb += Bc * Bc;
      }
    for (int off = 32; off; off >>= 1) {
      dab += __shfl_down(dab, off);
      daa += __shfl_down(daa, off);
      dbb += __shfl_down(dbb, off);
    }
    int wave = t >> 6, lane = t & 63;
    if (lane == 0) { wred[wave][0] = dab; wred[wave][1] = daa; wred[wave][2] = dbb; }
    __syncthreads();
    if (t == 0) {
      double w = diag ? 1.0 : 2.0;
      double s0 = 0, s1 = 0, s2 = 0;
      for (int q = 0; q < 4; ++q) { s0 += wred[q][0]; s1 += wred[q][1]; s2 += wred[q][2]; }
      atomicAdd(&ws[WS_DOTS + 0], w * s0);
      atomicAdd(&ws[WS_DOTS + 1], w * s1);
      atomicAdd(&ws[WS_DOTS + 2], w * s2);
    }
  }
}

// ---------------- mid: S = sum(u) ----------------
__global__ __launch_bounds__(256) void mid_kernel(double* __restrict__ ws) {
  const int t = threadIdx.x;
  double sa = 0, sb = 0;
  for (int i = t; i < NPTS; i += 256) { sa += ws[WS_U_A + i]; sb += ws[WS_U_B + i]; }
  for (int off = 32; off; off >>= 1) { sa += __shfl_down(sa, off); sb += __shfl_down(sb, off); }
  __shared__ double red[4][2];
  int wave = t >> 6, lane = t & 63;
  if (lane == 0) { red[wave][0] = sa; red[wave][1] = sb; }
  __syncthreads();
  if (t == 0) {
    double s0 = 0, s1 = 0;
    for (int q = 0; q < 4; ++q) { s0 += red[q][0]; s1 += red[q][1]; }
    ws[WS_S + 0] = s0;
    ws[WS_S + 1] = s1;
  }
}

// ---------------- final ----------------
__global__ void final_kernel(const double* __restrict__ ws, float* __restrict__ out) {
  if (threadIdx.x == 0) {
    const double n = (double)NPTS;
    const double denom = n * (n - 3.0);
    double dab = ws[WS_DOTS + 0] / denom;
    double daa = ws[WS_DOTS + 1] / denom;
    double dbb = ws[WS_DOTS + 2] / denom;
    double dn = sqrt(daa * dbb);
    if (dn < 1e-9) dn = 1e-9;
    out[0] = (float)(dab / dn);
  }
}

extern "C" void kernel_launch(void* const* d_in, const int* in_sizes, int n_in,
                              void* d_out, int out_size, void* d_ws, size_t ws_size,
                              hipStream_t stream) {
  const float* fa = (const float*)d_in[0];
  const float* fb = (const float*)d_in[1];
  double* ws = (double*)d_ws;

  hipMemsetAsync(d_ws, 0, WS_ZERO_DOUBLES * sizeof(double), stream);
  sq_kernel<<<dim3(NPTS / 4, 2), 256, 0, stream>>>(fa, fb, ws);
  tile_kernel<0><<<dim3(64, 64), 256, 0, stream>>>(fa, fb, ws);
  mid_kernel<<<1, 256, 0, stream>>>(ws);
  tile_kernel<1><<<dim3(64, 64), 256, 0, stream>>>(fa, fb, ws);
  final_kernel<<<1, 64, 0, stream>>>(ws, (float*)d_out);
}

// Round 5
// 441.683 us; speedup vs baseline: 1.7931x; 1.7931x over previous
//
#include <hip/hip_runtime.h>
#include <hip/hip_fp16.h>
#include <math.h>

typedef float f32x4 __attribute__((ext_vector_type(4)));
typedef unsigned short u16x8 __attribute__((ext_vector_type(8)));

#define NPTS 4096
#define DIM  512
#define BK   32
#define LDP  68
#define NTB  64                      // 64x64-elem tiles per side
#define NTILES (NTB*(NTB+1)/2)       // 2080 upper-tri tiles
#define TILE_ELEMS 4096              // 64*64

// ws layout: doubles region first, then fp16 distance tiles
#define WS_U_A   0
#define WS_U_B   4096
#define WS_S     8192
#define WS_DOTS  8194
#define WS_SQA   8197
#define WS_SQB   12293
#define WS_ZERO_DOUBLES 8197
#define WS_TILE_BYTE_OFF 262144ull   // tiles start at 256 KiB

__device__ __forceinline__ void tri_decode(int t, int& bi, int& bj) {
  int r = (int)((sqrt(8.0 * (double)t + 1.0) - 1.0) * 0.5);
  while ((r + 1) * (r + 2) / 2 <= t) ++r;
  while (r * (r + 1) / 2 > t) --r;
  bj = r; bi = t - r * (r + 1) / 2;   // bi <= bj
}

// ---------------- sq kernel: sq[i] = sum_k x[i][k]^2 (double) -------------
__global__ __launch_bounds__(256) void sq_kernel(const float* __restrict__ fa,
                                                 const float* __restrict__ fb,
                                                 double* __restrict__ ws) {
  int wave = threadIdx.x >> 6, lane = threadIdx.x & 63;
  int row = blockIdx.x * 4 + wave;
  const float* src = blockIdx.y ? fb : fa;
  double*      dst = blockIdx.y ? (ws + WS_SQB) : (ws + WS_SQA);
  const f32x4* p = (const f32x4*)(src + (size_t)row * DIM);
  double s = 0.0;
#pragma unroll
  for (int c = 0; c < DIM / 4 / 64; ++c) {
    f32x4 v = p[lane + c * 64];
    s += (double)v[0]*v[0] + (double)v[1]*v[1] + (double)v[2]*v[2] + (double)v[3]*v[3];
  }
  for (int off = 32; off; off >>= 1) s += __shfl_down(s, off);
  if (lane == 0) dst[row] = s;
}

// distance quantized to IEEE fp16 — matches the passing round bit-exactly
__device__ __forceinline__ double dist_q(double d2) {
  if (d2 <= 0.0) return 0.0;
  float d = (float)sqrt(d2);
  return (double)__half2float(__float2half(d));   // RNE
}

// ---------------- pass 1: Gram + fp16 distances + row sums (+ store tiles) ----------------
// 128 threads = 2 waves; wave0 handles A, wave1 handles B. 8x8 regs/thread.
__global__ __launch_bounds__(128, 2) void gram_kernel(
    const float* __restrict__ fa, const float* __restrict__ fb,
    double* __restrict__ ws,
    __half* __restrict__ dTA, __half* __restrict__ dTB, int store)
{
  int bi, bj; tri_decode(blockIdx.x, bi, bj);
  const int i0 = bi * 64, j0 = bj * 64;
  const bool diag = (bi == bj);

  __shared__ alignas(16) float sAI[BK][LDP];
  __shared__ alignas(16) float sAJ[BK][LDP];
  __shared__ alignas(16) float sBI[BK][LDP];
  __shared__ alignas(16) float sBJ[BK][LDP];

  const int t = threadIdx.x;
  const int wave = t >> 6, lane = t & 63;
  const int lx = lane & 7, ly = lane >> 3;

  float  acc[8][8];
  double accD[8][8];
#pragma unroll
  for (int m = 0; m < 8; ++m)
#pragma unroll
    for (int l = 0; l < 8; ++l) { acc[m][l] = 0.f; accD[m][l] = 0.0; }

  for (int k0 = 0; k0 < DIM; k0 += BK) {
    __syncthreads();
#pragma unroll
    for (int h = 0; h < 4; ++h) {
      int rr = (t >> 3) + h * 16;
      int cc = (t & 7) * 4;
      f32x4 va_i = *(const f32x4*)(fa + (size_t)(i0 + rr) * DIM + k0 + cc);
      f32x4 va_j = *(const f32x4*)(fa + (size_t)(j0 + rr) * DIM + k0 + cc);
      f32x4 vb_i = *(const f32x4*)(fb + (size_t)(i0 + rr) * DIM + k0 + cc);
      f32x4 vb_j = *(const f32x4*)(fb + (size_t)(j0 + rr) * DIM + k0 + cc);
#pragma unroll
      for (int u = 0; u < 4; ++u) {
        sAI[cc + u][rr] = va_i[u];
        sAJ[cc + u][rr] = va_j[u];
        sBI[cc + u][rr] = vb_i[u];
        sBJ[cc + u][rr] = vb_j[u];
      }
    }
    __syncthreads();

    const float* pI = wave ? &sBI[0][0] : &sAI[0][0];
    const float* pJ = wave ? &sBJ[0][0] : &sAJ[0][0];
#pragma unroll 4
    for (int kk = 0; kk < BK; ++kk) {
      f32x4 vI0 = *(const f32x4*)(pI + kk * LDP + ly * 8);
      f32x4 vI1 = *(const f32x4*)(pI + kk * LDP + ly * 8 + 4);
      f32x4 vJ0 = *(const f32x4*)(pJ + kk * LDP + lx * 8);
      f32x4 vJ1 = *(const f32x4*)(pJ + kk * LDP + lx * 8 + 4);
      float vi[8] = {vI0[0],vI0[1],vI0[2],vI0[3],vI1[0],vI1[1],vI1[2],vI1[3]};
      float vj[8] = {vJ0[0],vJ0[1],vJ0[2],vJ0[3],vJ1[0],vJ1[1],vJ1[2],vJ1[3]};
#pragma unroll
      for (int m = 0; m < 8; ++m)
#pragma unroll
        for (int l = 0; l < 8; ++l)
          acc[m][l] = fmaf(vi[m], vj[l], acc[m][l]);
    }
#pragma unroll
    for (int m = 0; m < 8; ++m)
#pragma unroll
      for (int l = 0; l < 8; ++l) {
        accD[m][l] += (double)acc[m][l];
        acc[m][l] = 0.f;
      }
  }

  // ---- epilogue: fp16-quantized distances, row/col sums, optional tile store ----
  const double* sqx = ws + (wave ? WS_SQB : WS_SQA);
  double*       ux  = ws + (wave ? WS_U_B : WS_U_A);
  __half*       dT  = wave ? dTB : dTA;

  double si[8], sj[8];
#pragma unroll
  for (int m = 0; m < 8; ++m) {
    si[m] = sqx[i0 + ly * 8 + m];
    sj[m] = sqx[j0 + lx * 8 + m];
  }
  double rs[8] = {0,0,0,0,0,0,0,0}, cs[8] = {0,0,0,0,0,0,0,0};
  const size_t tbase = (size_t)blockIdx.x * TILE_ELEMS;
#pragma unroll
  for (int m = 0; m < 8; ++m) {
    u16x8 pack;
#pragma unroll
    for (int l = 0; l < 8; ++l) {
      double d2 = si[m] + sj[l] - 2.0 * accD[m][l];
      unsigned short bits = 0;
      double dq = 0.0;
      if (d2 > 0.0) {
        float df = (float)sqrt(d2);
        __half h = __float2half(df);          // RNE, identical to dist_q
        bits = __half_as_ushort(h);
        dq = (double)__half2float(h);
      }
      if (diag && (ly * 8 + m == lx * 8 + l)) { bits = 0; dq = 0.0; }
      pack[l] = bits;
      rs[m] += dq;
      cs[l] += dq;
    }
    if (store) *(u16x8*)(dT + tbase + (size_t)(ly * 8 + m) * 64 + lx * 8) = pack;
  }

  // row sums -> u[i0 + row]: reduce over lx lanes (xor 1,2,4)
#pragma unroll
  for (int m = 0; m < 8; ++m) {
    double v = rs[m];
    v += __shfl_xor(v, 1); v += __shfl_xor(v, 2); v += __shfl_xor(v, 4);
    if (lx == 0) atomicAdd(&ux[i0 + ly * 8 + m], v);
  }
  if (!diag) {  // transposed entries: col sums -> u[j0 + col]
#pragma unroll
    for (int l = 0; l < 8; ++l) {
      double v = cs[l];
      v += __shfl_xor(v, 8); v += __shfl_xor(v, 16); v += __shfl_xor(v, 32);
      if (ly == 0) atomicAdd(&ux[j0 + lx * 8 + l], v);
    }
  }
}

// ---------------- mid: S = sum(u) ----------------
__global__ __launch_bounds__(256) void mid_kernel(double* __restrict__ ws) {
  const int t = threadIdx.x;
  double sa = 0, sb = 0;
  for (int i = t; i < NPTS; i += 256) { sa += ws[WS_U_A + i]; sb += ws[WS_U_B + i]; }
  for (int off = 32; off; off >>= 1) { sa += __shfl_down(sa, off); sb += __shfl_down(sb, off); }
  __shared__ double red[4][2];
  int wave = t >> 6, lane = t & 63;
  if (lane == 0) { red[wave][0] = sa; red[wave][1] = sb; }
  __syncthreads();
  if (t == 0) {
    double s0 = 0, s1 = 0;
    for (int q = 0; q < 4; ++q) { s0 += red[q][0]; s1 += red[q][1]; }
    ws[WS_S + 0] = s0;
    ws[WS_S + 1] = s1;
  }
}

// ---------------- pass 2 (fast): streaming U-centered dots over stored fp16 tiles ----------------
__global__ __launch_bounds__(256) void dot_kernel(
    double* __restrict__ ws,
    const __half* __restrict__ dTA, const __half* __restrict__ dTB)
{
  int bi, bj; tri_decode(blockIdx.x, bi, bj);
  const int i0 = bi * 64, j0 = bj * 64;
  const bool diag = (bi == bj);
  const int t = threadIdx.x;

  __shared__ double uai[64], uaj[64], ubi[64], ubj[64];
  __shared__ double wred[4][3];
  const double n = (double)NPTS, inv = 1.0 / (n - 2.0);
  if      (t < 64)  uai[t]       = ws[WS_U_A + i0 + t]         * inv;
  else if (t < 128) uaj[t - 64]  = ws[WS_U_A + j0 + (t - 64)]  * inv;
  else if (t < 192) ubi[t - 128] = ws[WS_U_B + i0 + (t - 128)] * inv;
  else              ubj[t - 192] = ws[WS_U_B + j0 + (t - 192)] * inv;
  __syncthreads();

  const double ta = ws[WS_S + 0] / ((n - 1.0) * (n - 2.0));
  const double tb = ws[WS_S + 1] / ((n - 1.0) * (n - 2.0));
  const int r = t >> 2, c0 = (t & 3) * 16;
  const size_t base = (size_t)blockIdx.x * TILE_ELEMS + (size_t)r * 64 + c0;
  const double rAi = uai[r], rBi = ubi[r];
  double dab = 0, daa = 0, dbb = 0;
#pragma unroll
  for (int g = 0; g < 2; ++g) {
    u16x8 va = *(const u16x8*)(dTA + base + g * 8);
    u16x8 vb = *(const u16x8*)(dTB + base + g * 8);
#pragma unroll
    for (int e = 0; e < 8; ++e) {
      int c = c0 + g * 8 + e;
      if (diag && r == c) continue;   // fill_diagonal_(0)
      double Ac = (double)__half2float(__ushort_as_half(va[e])) - rAi - uaj[c] + ta;
      double Bc = (double)__half2float(__ushort_as_half(vb[e])) - rBi - ubj[c] + tb;
      dab += Ac * Bc; daa += Ac * Ac; dbb += Bc * Bc;
    }
  }
  for (int off = 32; off; off >>= 1) {
    dab += __shfl_down(dab, off);
    daa += __shfl_down(daa, off);
    dbb += __shfl_down(dbb, off);
  }
  int wv = t >> 6, ln = t & 63;
  if (ln == 0) { wred[wv][0] = dab; wred[wv][1] = daa; wred[wv][2] = dbb; }
  __syncthreads();
  if (t == 0) {
    double w = diag ? 1.0 : 2.0;
    double s0 = 0, s1 = 0, s2 = 0;
    for (int q = 0; q < 4; ++q) { s0 += wred[q][0]; s1 += wred[q][1]; s2 += wred[q][2]; }
    atomicAdd(&ws[WS_DOTS + 0], w * s0);
    atomicAdd(&ws[WS_DOTS + 1], w * s1);
    atomicAdd(&ws[WS_DOTS + 2], w * s2);
  }
}

// ---------------- pass 2 (fallback): recompute distances (previous round's MODE1) ----------------
__global__ __launch_bounds__(256) void recompute_kernel(
    const float* __restrict__ fa, const float* __restrict__ fb,
    double* __restrict__ ws)
{
  const int bi = blockIdx.y, bj = blockIdx.x;
  if (bj < bi) return;

  __shared__ alignas(16) float sAI[BK][LDP];
  __shared__ alignas(16) float sAJ[BK][LDP];
  __shared__ alignas(16) float sBI[BK][LDP];
  __shared__ alignas(16) float sBJ[BK][LDP];
  __shared__ double wred[4][3];

  const int t  = threadIdx.x;
  const int tx = t & 15, ty = t >> 4;
  const int i0 = bi * 64, j0 = bj * 64;
  const bool diag = (bi == bj);

  double accAd[4][4] = {{0.0}}, accBd[4][4] = {{0.0}};

  for (int k0 = 0; k0 < DIM; k0 += BK) {
    __syncthreads();
#pragma unroll
    for (int h = 0; h < 2; ++h) {
      int rr = (t >> 3) + h * 32;
      int cc = (t & 7) * 4;
      f32x4 va_i = *(const f32x4*)(fa + (size_t)(i0 + rr) * DIM + k0 + cc);
      f32x4 va_j = *(const f32x4*)(fa + (size_t)(j0 + rr) * DIM + k0 + cc);
      f32x4 vb_i = *(const f32x4*)(fb + (size_t)(i0 + rr) * DIM + k0 + cc);
      f32x4 vb_j = *(const f32x4*)(fb + (size_t)(j0 + rr) * DIM + k0 + cc);
#pragma unroll
      for (int u = 0; u < 4; ++u) {
        sAI[cc + u][rr] = va_i[u];
        sAJ[cc + u][rr] = va_j[u];
        sBI[cc + u][rr] = vb_i[u];
        sBJ[cc + u][rr] = vb_j[u];
      }
    }
    __syncthreads();

    float accA[4][4] = {{0.f}}, accB[4][4] = {{0.f}};
#pragma unroll 4
    for (int kk = 0; kk < BK; ++kk) {
      f32x4 aI = *(const f32x4*)&sAI[kk][ty * 4];
      f32x4 aJ = *(const f32x4*)&sAJ[kk][tx * 4];
      f32x4 bI = *(const f32x4*)&sBI[kk][ty * 4];
      f32x4 bJ = *(const f32x4*)&sBJ[kk][tx * 4];
#pragma unroll
      for (int m = 0; m < 4; ++m)
#pragma unroll
        for (int l = 0; l < 4; ++l) {
          accA[m][l] = fmaf(aI[m], aJ[l], accA[m][l]);
          accB[m][l] = fmaf(bI[m], bJ[l], accB[m][l]);
        }
    }
#pragma unroll
    for (int m = 0; m < 4; ++m)
#pragma unroll
      for (int l = 0; l < 4; ++l) {
        accAd[m][l] += (double)accA[m][l];
        accBd[m][l] += (double)accB[m][l];
      }
  }

  const double* sqa = ws + WS_SQA;
  const double* sqb = ws + WS_SQB;
  double sia[4], sja[4], sib[4], sjb[4];
#pragma unroll
  for (int m = 0; m < 4; ++m) {
    sia[m] = sqa[i0 + ty * 4 + m];
    sib[m] = sqb[i0 + ty * 4 + m];
    sja[m] = sqa[j0 + tx * 4 + m];
    sjb[m] = sqb[j0 + tx * 4 + m];
  }
  double da[4][4], db[4][4];
#pragma unroll
  for (int m = 0; m < 4; ++m)
#pragma unroll
    for (int l = 0; l < 4; ++l) {
      da[m][l] = dist_q(sia[m] + sja[l] - 2.0 * accAd[m][l]);
      db[m][l] = dist_q(sib[m] + sjb[l] - 2.0 * accBd[m][l]);
      if (diag && (ty * 4 + m == tx * 4 + l)) { da[m][l] = 0.0; db[m][l] = 0.0; }
    }

  const double n = (double)NPTS;
  const double inv_nm2 = 1.0 / (n - 2.0);
  const double* uA = ws + WS_U_A;
  const double* uB = ws + WS_U_B;
  const double SA = ws[WS_S + 0], SB = ws[WS_S + 1];
  const double ta = SA / ((n - 1.0) * (n - 2.0));
  const double tb = SB / ((n - 1.0) * (n - 2.0));
  double rai[4], rbi[4], raj[4], rbj[4];
#pragma unroll
  for (int m = 0; m < 4; ++m) {
    rai[m] = uA[i0 + ty * 4 + m] * inv_nm2;
    rbi[m] = uB[i0 + ty * 4 + m] * inv_nm2;
    raj[m] = uA[j0 + tx * 4 + m] * inv_nm2;
    rbj[m] = uB[j0 + tx * 4 + m] * inv_nm2;
  }
  double dab = 0, daa = 0, dbb = 0;
#pragma unroll
  for (int m = 0; m < 4; ++m)
#pragma unroll
    for (int l = 0; l < 4; ++l) {
      double Ac = da[m][l] - rai[m] - raj[l] + ta;
      double Bc = db[m][l] - rbi[m] - rbj[l] + tb;
      if (diag && (ty * 4 + m == tx * 4 + l)) { Ac = 0.0; Bc = 0.0; }
      dab += Ac * Bc;
      daa += Ac * Ac;
      dbb += Bc * Bc;
    }
  for (int off = 32; off; off >>= 1) {
    dab += __shfl_down(dab, off);
    daa += __shfl_down(daa, off);
    dbb += __shfl_down(dbb, off);
  }
  int wave = t >> 6, lane = t & 63;
  if (lane == 0) { wred[wave][0] = dab; wred[wave][1] = daa; wred[wave][2] = dbb; }
  __syncthreads();
  if (t == 0) {
    double w = diag ? 1.0 : 2.0;
    double s0 = 0, s1 = 0, s2 = 0;
    for (int q = 0; q < 4; ++q) { s0 += wred[q][0]; s1 += wred[q][1]; s2 += wred[q][2]; }
    atomicAdd(&ws[WS_DOTS + 0], w * s0);
    atomicAdd(&ws[WS_DOTS + 1], w * s1);
    atomicAdd(&ws[WS_DOTS + 2], w * s2);
  }
}

// ---------------- final ----------------
__global__ void final_kernel(const double* __restrict__ ws, float* __restrict__ out) {
  if (threadIdx.x == 0) {
    const double n = (double)NPTS;
    const double denom = n * (n - 3.0);
    double dab = ws[WS_DOTS + 0] / denom;
    double daa = ws[WS_DOTS + 1] / denom;
    double dbb = ws[WS_DOTS + 2] / denom;
    double dn = sqrt(daa * dbb);
    if (dn < 1e-9) dn = 1e-9;
    out[0] = (float)(dab / dn);
  }
}

extern "C" void kernel_launch(void* const* d_in, const int* in_sizes, int n_in,
                              void* d_out, int out_size, void* d_ws, size_t ws_size,
                              hipStream_t stream) {
  const float* fa = (const float*)d_in[0];
  const float* fb = (const float*)d_in[1];
  double* ws = (double*)d_ws;

  const size_t tile_halves = (size_t)NTILES * TILE_ELEMS;
  const size_t need = WS_TILE_BYTE_OFF + 2ull * tile_halves * sizeof(__half);
  const int store = (ws_size >= need) ? 1 : 0;
  __half* dTA = (__half*)((char*)d_ws + WS_TILE_BYTE_OFF);
  __half* dTB = dTA + tile_halves;

  hipMemsetAsync(d_ws, 0, WS_ZERO_DOUBLES * sizeof(double), stream);
  sq_kernel<<<dim3(NPTS / 4, 2), 256, 0, stream>>>(fa, fb, ws);
  gram_kernel<<<NTILES, 128, 0, stream>>>(fa, fb, ws, dTA, dTB, store);
  mid_kernel<<<1, 256, 0, stream>>>(ws);
  if (store) {
    dot_kernel<<<NTILES, 256, 0, stream>>>(ws, dTA, dTB);
  } else {
    recompute_kernel<<<dim3(64, 64), 256, 0, stream>>>(fa, fb, ws);
  }
  final_kernel<<<1, 64, 0, stream>>>(ws, (float*)d_out);
}

// Round 6
// 404.123 us; speedup vs baseline: 1.9597x; 1.0929x over previous
//
#include <hip/hip_runtime.h>
#include <hip/hip_fp16.h>
#include <math.h>

typedef float f32x4 __attribute__((ext_vector_type(4)));
typedef unsigned short u16x8 __attribute__((ext_vector_type(8)));

#define NPTS 4096
#define DIM  512
#define BK   32
#define LDP  68
#define NTB  64
#define NTILES (NTB*(NTB+1)/2)       // 2080 upper-tri tiles

// ws layout (doubles)
#define WS_U_A   0
#define WS_U_B   4096
#define WS_PAB   8192
#define WS_PAA   (8192 + NTILES)
#define WS_PBB   (8192 + 2*NTILES)
#define WS_SQA   (8192 + 3*NTILES)
#define WS_SQB   (WS_SQA + NPTS)
#define WS_ZERO_DOUBLES WS_SQA

__device__ __forceinline__ void tri_decode(int t, int& bi, int& bj) {
  int r = (int)((sqrt(8.0 * (double)t + 1.0) - 1.0) * 0.5);
  while ((r + 1) * (r + 2) / 2 <= t) ++r;
  while (r * (r + 1) / 2 > t) --r;
  bj = r; bi = t - r * (r + 1) / 2;   // bi <= bj
}

// ---------------- sq kernel: sq[i] = sum_k x[i][k]^2 (double) -------------
__global__ __launch_bounds__(256) void sq_kernel(const float* __restrict__ fa,
                                                 const float* __restrict__ fb,
                                                 double* __restrict__ ws) {
  int wave = threadIdx.x >> 6, lane = threadIdx.x & 63;
  int row = blockIdx.x * 4 + wave;
  const float* src = blockIdx.y ? fb : fa;
  double*      dst = blockIdx.y ? (ws + WS_SQB) : (ws + WS_SQA);
  const f32x4* p = (const f32x4*)(src + (size_t)row * DIM);
  double s = 0.0;
#pragma unroll
  for (int c = 0; c < DIM / 4 / 64; ++c) {
    f32x4 v = p[lane + c * 64];
    s += (double)v[0]*v[0] + (double)v[1]*v[1] + (double)v[2]*v[2] + (double)v[3]*v[3];
  }
  for (int off = 32; off; off >>= 1) s += __shfl_down(s, off);
  if (lane == 0) dst[row] = s;
}

// ---------------- fused gram + fp16 distances + all statistics ----------------
// 256 threads = 4 waves. wave = {mat = wave>>1 (0:A,1:B), half = wave&1 (rows 0-31 / 32-63)}.
// Thread tile 4x8: rows half*32+ly*4+m, cols lx*8+l.
// NUMERICS FROZEN (match passing round bit-exactly): per-(i,j) fp32 fmaf chain in
// kk-ascending order within each BK=32 tile, f64 flush per tile, d2 = si+sj-2*accD,
// d = fp16_rne((float)sqrt(d2)), diagonal forced 0.
__global__ __launch_bounds__(256, 3) void gram_kernel(
    const float* __restrict__ fa, const float* __restrict__ fb,
    double* __restrict__ ws)
{
  int bi, bj; tri_decode(blockIdx.x, bi, bj);
  const int i0 = bi * 64, j0 = bj * 64;
  const bool diag = (bi == bj);

  __shared__ alignas(16) float sAI[BK][LDP];
  __shared__ alignas(16) float sAJ[BK][LDP];
  __shared__ alignas(16) float sBI[BK][LDP];
  __shared__ alignas(16) float sBJ[BK][LDP];
  __shared__ double wred[4][2];
  // after the k-loop the staging LDS is dead; B waves publish their fp16 bits here
  unsigned short* dbufB = (unsigned short*)&sAI[0][0];   // 64 rows x 72 u16 = 9216 B

  const int t    = threadIdx.x;
  const int wave = t >> 6, lane = t & 63;
  const int mat  = wave >> 1, half = wave & 1;
  const int lx   = lane & 7,  ly   = lane >> 3;

  float  acc[4][8];
  double accD[4][8];
#pragma unroll
  for (int m = 0; m < 4; ++m)
#pragma unroll
    for (int l = 0; l < 8; ++l) { acc[m][l] = 0.f; accD[m][l] = 0.0; }

  const int srow = t >> 3;         // 0..31
  const int scol = (t & 7) * 4;    // 0..28

  const float* pI = (mat ? &sBI[0][0] : &sAI[0][0]) + half * 32 + ly * 4;
  const float* pJ = (mat ? &sBJ[0][0] : &sAJ[0][0]) + lx * 8;

  for (int k0 = 0; k0 < DIM; k0 += BK) {
    __syncthreads();
#pragma unroll
    for (int h = 0; h < 2; ++h) {
      int rr = srow + h * 32;
      f32x4 va_i = *(const f32x4*)(fa + (size_t)(i0 + rr) * DIM + k0 + scol);
      f32x4 va_j = *(const f32x4*)(fa + (size_t)(j0 + rr) * DIM + k0 + scol);
      f32x4 vb_i = *(const f32x4*)(fb + (size_t)(i0 + rr) * DIM + k0 + scol);
      f32x4 vb_j = *(const f32x4*)(fb + (size_t)(j0 + rr) * DIM + k0 + scol);
#pragma unroll
      for (int u = 0; u < 4; ++u) {
        sAI[scol + u][rr] = va_i[u];
        sAJ[scol + u][rr] = va_j[u];
        sBI[scol + u][rr] = vb_i[u];
        sBJ[scol + u][rr] = vb_j[u];
      }
    }
    __syncthreads();

#pragma unroll 8
    for (int kk = 0; kk < BK; ++kk) {
      f32x4 vI  = *(const f32x4*)(pI + kk * LDP);
      f32x4 vJ0 = *(const f32x4*)(pJ + kk * LDP);
      f32x4 vJ1 = *(const f32x4*)(pJ + kk * LDP + 4);
#pragma unroll
      for (int m = 0; m < 4; ++m) {
#pragma unroll
        for (int l = 0; l < 4; ++l) {
          acc[m][l]     = fmaf(vI[m], vJ0[l], acc[m][l]);
          acc[m][l + 4] = fmaf(vI[m], vJ1[l], acc[m][l + 4]);
        }
      }
    }
    // f64 flush per BK tile (frozen cadence)
#pragma unroll
    for (int m = 0; m < 4; ++m)
#pragma unroll
      for (int l = 0; l < 8; ++l) {
        accD[m][l] += (double)acc[m][l];
        acc[m][l] = 0.f;
      }
  }

  __syncthreads();   // staging LDS now dead; safe to reuse as dbufB

  // ---- distances (fp16-quantized) + per-thread stats ----
  const double* sqx = ws + (mat ? WS_SQB : WS_SQA);
  double*       ux  = ws + (mat ? WS_U_B : WS_U_A);

  double si[4], sj[8];
#pragma unroll
  for (int m = 0; m < 4; ++m) si[m] = sqx[i0 + half * 32 + ly * 4 + m];
#pragma unroll
  for (int l = 0; l < 8; ++l) sj[l] = sqx[j0 + lx * 8 + l];

  double rs[4] = {0,0,0,0}, cs[8] = {0,0,0,0,0,0,0,0};
  double self = 0.0;
  u16x8 pk[4];
#pragma unroll
  for (int m = 0; m < 4; ++m) {
#pragma unroll
    for (int l = 0; l < 8; ++l) {
      double d2 = si[m] + sj[l] - 2.0 * accD[m][l];
      unsigned short bits = 0;
      double dq = 0.0;
      if (d2 > 0.0) {
        float df = (float)sqrt(d2);
        __half h = __float2half(df);          // RNE — frozen quantization
        bits = __half_as_ushort(h);
        dq = (double)__half2float(h);
      }
      if (diag && (half * 32 + ly * 4 + m == lx * 8 + l)) { bits = 0; dq = 0.0; }
      pk[m][l] = bits;
      rs[m] += dq;
      cs[l] += dq;
      self  += dq * dq;
    }
  }
  if (mat == 1) {
#pragma unroll
    for (int m = 0; m < 4; ++m)
      *(u16x8*)(dbufB + (size_t)(half * 32 + ly * 4 + m) * 72 + lx * 8) = pk[m];
  }

  // row sums -> u[i0+row] (reduce over lx: xor 1,2,4)
#pragma unroll
  for (int m = 0; m < 4; ++m) {
    double v = rs[m];
    v += __shfl_xor(v, 1); v += __shfl_xor(v, 2); v += __shfl_xor(v, 4);
    if (lx == 0) atomicAdd(&ux[i0 + half * 32 + ly * 4 + m], v);
  }
  if (!diag) {  // transposed entries: col sums -> u[j0+col] (reduce over ly: xor 8,16,32)
#pragma unroll
    for (int l = 0; l < 8; ++l) {
      double v = cs[l];
      v += __shfl_xor(v, 8); v += __shfl_xor(v, 16); v += __shfl_xor(v, 32);
      if (ly == 0) atomicAdd(&ux[j0 + lx * 8 + l], v);
    }
  }

  __syncthreads();   // dbufB fully written

  double pab = 0.0;
  if (mat == 0) {
#pragma unroll
    for (int m = 0; m < 4; ++m) {
      u16x8 db = *(const u16x8*)(dbufB + (size_t)(half * 32 + ly * 4 + m) * 72 + lx * 8);
#pragma unroll
      for (int l = 0; l < 8; ++l)
        pab += (double)__half2float(__ushort_as_half(pk[m][l]))
             * (double)__half2float(__ushort_as_half(db[l]));
    }
  }

  for (int off = 32; off; off >>= 1) {
    pab  += __shfl_down(pab, off);
    self += __shfl_down(self, off);
  }
  if (lane == 0) {
    wred[wave][0] = (mat == 0) ? pab : self;   // A: pab, B: pbb
    wred[wave][1] = (mat == 0) ? self : 0.0;   // A: paa
  }
  __syncthreads();
  if (t == 0) {
    double w = diag ? 1.0 : 2.0;
    ws[WS_PAB + blockIdx.x] = w * (wred[0][0] + wred[1][0]);
    ws[WS_PAA + blockIdx.x] = w * (wred[0][1] + wred[1][1]);
    ws[WS_PBB + blockIdx.x] = w * (wred[2][0] + wred[3][0]);
  }
}

// ---------------- final: reduce stats, closed-form U-centered dots --------------------
// Closed form verified equal to the literal two-pass (rounds 2<->3, bit-identical absmax).
__global__ __launch_bounds__(256) void final_kernel(const double* __restrict__ ws,
                                                    float* __restrict__ out)
{
  const int t = threadIdx.x;
  double sa = 0, sb = 0, uab = 0, uaa = 0, ubb = 0, ab = 0, aa = 0, bb = 0;
  for (int i = t; i < NPTS; i += 256) {
    double a = ws[WS_U_A + i], b = ws[WS_U_B + i];
    sa += a; sb += b; uab += a * b; uaa += a * a; ubb += b * b;
  }
  for (int i = t; i < NTILES; i += 256) {
    ab += ws[WS_PAB + i]; aa += ws[WS_PAA + i]; bb += ws[WS_PBB + i];
  }
  for (int off = 32; off; off >>= 1) {
    sa  += __shfl_down(sa, off);  sb  += __shfl_down(sb, off);
    uab += __shfl_down(uab, off); uaa += __shfl_down(uaa, off); ubb += __shfl_down(ubb, off);
    ab  += __shfl_down(ab, off);  aa  += __shfl_down(aa, off);  bb  += __shfl_down(bb, off);
  }
  __shared__ double red[4][8];
  int wave = t >> 6, lane = t & 63;
  if (lane == 0) {
    red[wave][0] = sa;  red[wave][1] = sb;  red[wave][2] = uab; red[wave][3] = uaa;
    red[wave][4] = ubb; red[wave][5] = ab;  red[wave][6] = aa;  red[wave][7] = bb;
  }
  __syncthreads();
  if (t == 0) {
    double v[8] = {0,0,0,0,0,0,0,0};
    for (int q = 0; q < 4; ++q) for (int z = 0; z < 8; ++z) v[z] += red[q][z];
    const double SA = v[0], SB = v[1], UAB = v[2], UAA = v[3], UBB = v[4];
    const double PAB = v[5], PAA = v[6], PBB = v[7];
    const double n = (double)NPTS, nm2 = n - 2.0;
    auto dotv = [&](double P, double U, double sx, double sy) {
      double tX = sx / ((n - 1.0) * nm2), tY = sy / ((n - 1.0) * nm2);
      double RX = sx / nm2, RY = sy / nm2;
      double su  = U / nm2;
      double srr = U / (nm2 * nm2);
      double full = P - 4.0 * su + tY * sx + tX * sy + 2.0 * n * srr + 2.0 * RX * RY
                  - 2.0 * n * tY * RX - 2.0 * n * tX * RY + n * n * tX * tY;
      double dg = n * tX * tY - 2.0 * tX * RY - 2.0 * tY * RX + 4.0 * srr;
      return full - dg;
    };
    const double denomc = n * (n - 3.0);
    double dab = dotv(PAB, UAB, SA, SB) / denomc;
    double daa = dotv(PAA, UAA, SA, SA) / denomc;
    double dbb = dotv(PBB, UBB, SB, SB) / denomc;
    double dn = sqrt(daa * dbb);
    if (dn < 1e-9) dn = 1e-9;
    out[0] = (float)(dab / dn);
  }
}

extern "C" void kernel_launch(void* const* d_in, const int* in_sizes, int n_in,
                              void* d_out, int out_size, void* d_ws, size_t ws_size,
                              hipStream_t stream) {
  const float* fa = (const float*)d_in[0];
  const float* fb = (const float*)d_in[1];
  double* ws = (double*)d_ws;

  hipMemsetAsync(d_ws, 0, WS_ZERO_DOUBLES * sizeof(double), stream);
  sq_kernel<<<dim3(NPTS / 4, 2), 256, 0, stream>>>(fa, fb, ws);
  gram_kernel<<<NTILES, 256, 0, stream>>>(fa, fb, ws);
  final_kernel<<<1, 256, 0, stream>>>(ws, (float*)d_out);
}

// Round 7
// 384.628 us; speedup vs baseline: 2.0591x; 1.0507x over previous
//
#include <hip/hip_runtime.h>
#include <hip/hip_fp16.h>
#include <math.h>

typedef float f32x4 __attribute__((ext_vector_type(4)));
typedef unsigned short u16x8 __attribute__((ext_vector_type(8)));

#define NPTS 4096
#define DIM  512
#define BK   32
#define LDP  68
#define NTB  64
#define NTILES (NTB*(NTB+1)/2)       // 2080 upper-tri tiles

// ws layout (doubles)
#define WS_U_A   0
#define WS_U_B   4096
#define WS_PAB   8192
#define WS_PAA   (8192 + NTILES)
#define WS_PBB   (8192 + 2*NTILES)
#define WS_SQA   (8192 + 3*NTILES)
#define WS_SQB   (WS_SQA + NPTS)
#define WS_ZERO_DOUBLES WS_SQA

__device__ __forceinline__ void tri_decode(int t, int& bi, int& bj) {
  int r = (int)((sqrt(8.0 * (double)t + 1.0) - 1.0) * 0.5);
  while ((r + 1) * (r + 2) / 2 <= t) ++r;
  while (r * (r + 1) / 2 > t) --r;
  bj = r; bi = t - r * (r + 1) / 2;   // bi <= bj
}

// ---------------- sq kernel: sq[i] = sum_k x[i][k]^2 (double) -------------
__global__ __launch_bounds__(256) void sq_kernel(const float* __restrict__ fa,
                                                 const float* __restrict__ fb,
                                                 double* __restrict__ ws) {
  int wave = threadIdx.x >> 6, lane = threadIdx.x & 63;
  int row = blockIdx.x * 4 + wave;
  const float* src = blockIdx.y ? fb : fa;
  double*      dst = blockIdx.y ? (ws + WS_SQB) : (ws + WS_SQA);
  const f32x4* p = (const f32x4*)(src + (size_t)row * DIM);
  double s = 0.0;
#pragma unroll
  for (int c = 0; c < DIM / 4 / 64; ++c) {
    f32x4 v = p[lane + c * 64];
    s += (double)v[0]*v[0] + (double)v[1]*v[1] + (double)v[2]*v[2] + (double)v[3]*v[3];
  }
  for (int off = 32; off; off >>= 1) s += __shfl_down(s, off);
  if (lane == 0) dst[row] = s;
}

// ---------------- fused gram + fp16 distances + all statistics ----------------
// 128 threads = 2 waves: wave0 -> matrix A, wave1 -> matrix B. 8x8 tile/thread.
// NUMERICS FROZEN: per-(i,j) fp32 fmaf chain, kk ascending within each BK=32
// chunk, f64 flush per chunk, d2 = si+sj-2*accD, d = fp16_rne((float)sqrt(d2)),
// diagonal forced 0. (Thread remapping is bit-invariant: rounds 4->5->6.)
__global__ __attribute__((amdgpu_waves_per_eu(2, 2))) __launch_bounds__(128)
void gram_kernel(const float* __restrict__ fa, const float* __restrict__ fb,
                 double* __restrict__ ws)
{
  int bi, bj; tri_decode(blockIdx.x, bi, bj);
  const int i0 = bi * 64, j0 = bj * 64;
  const bool diag = (bi == bj);

  __shared__ alignas(16) float smem[4 * BK * LDP];   // 34816 B staging
  float* sAI_ = smem;
  float* sAJ_ = smem + BK * LDP;
  float* sBI_ = smem + 2 * BK * LDP;
  float* sBJ_ = smem + 3 * BK * LDP;
  __shared__ double wred[2][2];
  // after the k-loop the staging LDS is dead; wave1 publishes fp16 bits here
  unsigned short* dbufB = (unsigned short*)smem;     // 64 rows x 72 u16 = 9216 B

  const int t    = threadIdx.x;
  const int wave = t >> 6, lane = t & 63;
  const int lx   = lane & 7, ly = lane >> 3;

  float  acc[8][8];
  double accD[8][8];
#pragma unroll
  for (int m = 0; m < 8; ++m)
#pragma unroll
    for (int l = 0; l < 8; ++l) { acc[m][l] = 0.f; accD[m][l] = 0.0; }

  const int rr = lane;                         // staging row = lane (0..63)
  const float* pI = (wave ? sBI_ : sAI_) + ly * 8;
  const float* pJ = (wave ? sBJ_ : sAJ_) + lx * 8;

  for (int k0 = 0; k0 < DIM; k0 += BK) {
    __syncthreads();
    // stage 4 panels, [k][row] layout; each ds_write wave covers all 32 banks
    for (int h = 0; h < 4; ++h) {
      int cc = (h * 2 + wave) * 4;             // k-quad 0..7
      f32x4 va_i = *(const f32x4*)(fa + (size_t)(i0 + rr) * DIM + k0 + cc);
      f32x4 va_j = *(const f32x4*)(fa + (size_t)(j0 + rr) * DIM + k0 + cc);
      f32x4 vb_i = *(const f32x4*)(fb + (size_t)(i0 + rr) * DIM + k0 + cc);
      f32x4 vb_j = *(const f32x4*)(fb + (size_t)(j0 + rr) * DIM + k0 + cc);
#pragma unroll
      for (int u = 0; u < 4; ++u) {
        sAI_[(cc + u) * LDP + rr] = va_i[u];
        sAJ_[(cc + u) * LDP + rr] = va_j[u];
        sBI_[(cc + u) * LDP + rr] = vb_i[u];
        sBJ_[(cc + u) * LDP + rr] = vb_j[u];
      }
    }
    __syncthreads();

#pragma unroll 2
    for (int kk = 0; kk < BK; ++kk) {
      f32x4 vI0 = *(const f32x4*)(pI + kk * LDP);
      f32x4 vI1 = *(const f32x4*)(pI + kk * LDP + 4);
      f32x4 vJ0 = *(const f32x4*)(pJ + kk * LDP);
      f32x4 vJ1 = *(const f32x4*)(pJ + kk * LDP + 4);
      float vi[8] = {vI0[0],vI0[1],vI0[2],vI0[3],vI1[0],vI1[1],vI1[2],vI1[3]};
      float vj[8] = {vJ0[0],vJ0[1],vJ0[2],vJ0[3],vJ1[0],vJ1[1],vJ1[2],vJ1[3]};
#pragma unroll
      for (int m = 0; m < 8; ++m)
#pragma unroll
        for (int l = 0; l < 8; ++l)
          acc[m][l] = fmaf(vi[m], vj[l], acc[m][l]);
    }
    // f64 flush per BK chunk (frozen cadence)
#pragma unroll
    for (int m = 0; m < 8; ++m)
#pragma unroll
      for (int l = 0; l < 8; ++l) {
        accD[m][l] += (double)acc[m][l];
        acc[m][l] = 0.f;
      }
  }

  __syncthreads();   // staging LDS dead; safe to reuse as dbufB

  // ---- distances (fp16-quantized) + per-thread stats ----
  const double* sqx = ws + (wave ? WS_SQB : WS_SQA);
  double*       ux  = ws + (wave ? WS_U_B : WS_U_A);

  double si[8], sj[8];
#pragma unroll
  for (int m = 0; m < 8; ++m) si[m] = sqx[i0 + ly * 8 + m];
#pragma unroll
  for (int l = 0; l < 8; ++l) sj[l] = sqx[j0 + lx * 8 + l];

  double rs[8] = {0,0,0,0,0,0,0,0}, cs[8] = {0,0,0,0,0,0,0,0};
  double self = 0.0;
  u16x8 pk[8];
#pragma unroll
  for (int m = 0; m < 8; ++m) {
#pragma unroll
    for (int l = 0; l < 8; ++l) {
      double d2 = si[m] + sj[l] - 2.0 * accD[m][l];
      unsigned short bits = 0;
      double dq = 0.0;
      if (d2 > 0.0) {
        float df = (float)sqrt(d2);
        __half h = __float2half(df);          // RNE — frozen quantization
        bits = __half_as_ushort(h);
        dq = (double)__half2float(h);
      }
      if (diag && (ly * 8 + m == lx * 8 + l)) { bits = 0; dq = 0.0; }
      pk[m][l] = bits;
      rs[m] += dq;
      cs[l] += dq;
      self  += dq * dq;
    }
  }
  if (wave == 1) {
#pragma unroll
    for (int m = 0; m < 8; ++m)
      *(u16x8*)(dbufB + (size_t)(ly * 8 + m) * 72 + lx * 8) = pk[m];
  }

  // row sums -> u[i0+row] (reduce over lx: xor 1,2,4 — tree identical to prior rounds)
#pragma unroll
  for (int m = 0; m < 8; ++m) {
    double v = rs[m];
    v += __shfl_xor(v, 1); v += __shfl_xor(v, 2); v += __shfl_xor(v, 4);
    if (lx == 0) atomicAdd(&ux[i0 + ly * 8 + m], v);
  }
  if (!diag) {  // transposed entries: col sums -> u[j0+col] (reduce over ly)
#pragma unroll
    for (int l = 0; l < 8; ++l) {
      double v = cs[l];
      v += __shfl_xor(v, 8); v += __shfl_xor(v, 16); v += __shfl_xor(v, 32);
      if (ly == 0) atomicAdd(&ux[j0 + lx * 8 + l], v);
    }
  }

  __syncthreads();   // dbufB fully written

  double pab = 0.0;
  if (wave == 0) {
#pragma unroll
    for (int m = 0; m < 8; ++m) {
      u16x8 db = *(const u16x8*)(dbufB + (size_t)(ly * 8 + m) * 72 + lx * 8);
#pragma unroll
      for (int l = 0; l < 8; ++l)
        pab += (double)__half2float(__ushort_as_half(pk[m][l]))
             * (double)__half2float(__ushort_as_half(db[l]));
    }
  }

  for (int off = 32; off; off >>= 1) {
    pab  += __shfl_down(pab, off);
    self += __shfl_down(self, off);
  }
  if (lane == 0) {
    wred[wave][0] = (wave == 0) ? pab  : self;   // wave0: pab, wave1: pbb
    wred[wave][1] = (wave == 0) ? self : 0.0;    // wave0: paa
  }
  __syncthreads();
  if (t == 0) {
    double w = diag ? 1.0 : 2.0;
    ws[WS_PAB + blockIdx.x] = w * wred[0][0];
    ws[WS_PAA + blockIdx.x] = w * wred[0][1];
    ws[WS_PBB + blockIdx.x] = w * wred[1][0];
  }
}

// ---------------- final: reduce stats, closed-form U-centered dots --------------------
__global__ __launch_bounds__(256) void final_kernel(const double* __restrict__ ws,
                                                    float* __restrict__ out)
{
  const int t = threadIdx.x;
  double sa = 0, sb = 0, uab = 0, uaa = 0, ubb = 0, ab = 0, aa = 0, bb = 0;
  for (int i = t; i < NPTS; i += 256) {
    double a = ws[WS_U_A + i], b = ws[WS_U_B + i];
    sa += a; sb += b; uab += a * b; uaa += a * a; ubb += b * b;
  }
  for (int i = t; i < NTILES; i += 256) {
    ab += ws[WS_PAB + i]; aa += ws[WS_PAA + i]; bb += ws[WS_PBB + i];
  }
  for (int off = 32; off; off >>= 1) {
    sa  += __shfl_down(sa, off);  sb  += __shfl_down(sb, off);
    uab += __shfl_down(uab, off); uaa += __shfl_down(uaa, off); ubb += __shfl_down(ubb, off);
    ab  += __shfl_down(ab, off);  aa  += __shfl_down(aa, off);  bb  += __shfl_down(bb, off);
  }
  __shared__ double red[4][8];
  int wave = t >> 6, lane = t & 63;
  if (lane == 0) {
    red[wave][0] = sa;  red[wave][1] = sb;  red[wave][2] = uab; red[wave][3] = uaa;
    red[wave][4] = ubb; red[wave][5] = ab;  red[wave][6] = aa;  red[wave][7] = bb;
  }
  __syncthreads();
  if (t == 0) {
    double v[8] = {0,0,0,0,0,0,0,0};
    for (int q = 0; q < 4; ++q) for (int z = 0; z < 8; ++z) v[z] += red[q][z];
    const double SA = v[0], SB = v[1], UAB = v[2], UAA = v[3], UBB = v[4];
    const double PAB = v[5], PAA = v[6], PBB = v[7];
    const double n = (double)NPTS, nm2 = n - 2.0;
    auto dotv = [&](double P, double U, double sx, double sy) {
      double tX = sx / ((n - 1.0) * nm2), tY = sy / ((n - 1.0) * nm2);
      double RX = sx / nm2, RY = sy / nm2;
      double su  = U / nm2;
      double srr = U / (nm2 * nm2);
      double full = P - 4.0 * su + tY * sx + tX * sy + 2.0 * n * srr + 2.0 * RX * RY
                  - 2.0 * n * tY * RX - 2.0 * n * tX * RY + n * n * tX * tY;
      double dg = n * tX * tY - 2.0 * tX * RY - 2.0 * tY * RX + 4.0 * srr;
      return full - dg;
    };
    const double denomc = n * (n - 3.0);
    double dab = dotv(PAB, UAB, SA, SB) / denomc;
    double daa = dotv(PAA, UAA, SA, SA) / denomc;
    double dbb = dotv(PBB, UBB, SB, SB) / denomc;
    double dn = sqrt(daa * dbb);
    if (dn < 1e-9) dn = 1e-9;
    out[0] = (float)(dab / dn);
  }
}

extern "C" void kernel_launch(void* const* d_in, const int* in_sizes, int n_in,
                              void* d_out, int out_size, void* d_ws, size_t ws_size,
                              hipStream_t stream) {
  const float* fa = (const float*)d_in[0];
  const float* fb = (const float*)d_in[1];
  double* ws = (double*)d_ws;

  hipMemsetAsync(d_ws, 0, WS_ZERO_DOUBLES * sizeof(double), stream);
  sq_kernel<<<dim3(NPTS / 4, 2), 256, 0, stream>>>(fa, fb, ws);
  gram_kernel<<<NTILES, 128, 0, stream>>>(fa, fb, ws);
  final_kernel<<<1, 256, 0, stream>>>(ws, (float*)d_out);
}